// Round 3
// baseline (6304.971 us; speedup 1.0000x reference)
//
#include <hip/hip_runtime.h>
#include <cstdint>
#include <cstddef>

typedef unsigned short u16;
typedef unsigned char u8;
typedef unsigned int u32;

typedef short s16x8 __attribute__((ext_vector_type(8)));
typedef float f32x4 __attribute__((ext_vector_type(4)));

// ---------------- helpers ----------------
__device__ __forceinline__ float b2f(u16 h){ u32 u = ((u32)h)<<16; float f; __builtin_memcpy(&f,&u,4); return f; }
__device__ __forceinline__ u16 f2b(float x){ u32 u; __builtin_memcpy(&u,&x,4); u += 0x7fffu + ((u>>16)&1u); return (u16)(u>>16); }
__device__ __forceinline__ float sigf(float x){ return 1.f/(1.f+__expf(-x)); }
__device__ __forceinline__ float tanh2(float x){
  float ax=fabsf(x); float e=__expf(-2.f*ax); float r=(1.f-e)/(1.f+e); return x<0.f? -r : r;
}

typedef __attribute__((address_space(1))) const void gvoid_t;
typedef __attribute__((address_space(3))) void lvoid_t;
__device__ __forceinline__ void gl_lds16(const u16* src, u16* dst){
  __builtin_amdgcn_global_load_lds((gvoid_t*)src, (lvoid_t*)dst, 16, 0, 0);
}

// ---------------- mask dtype detection + canonicalization ----------------
__global__ void detect_mask_mode(const u8* raw, int n, int* flag){
  __shared__ int cnt;
  int tid = threadIdx.x;
  if(tid==0) cnt=0;
  __syncthreads();
  int c=0;
  for(int i=tid;i<n;i+=blockDim.x) c += (raw[i]!=0);
  atomicAdd(&cnt, c);
  __syncthreads();
  if(tid==0) *flag = (cnt > (n>>2)) ? 1 : 0;  // 1 => byte-per-element layout
}

__global__ void convert_masks(const void* done_raw, const void* main_raw, u8* done_u8, u8* main_u8, int n, const int* flag){
  int mode = *flag;
  for(int i = blockIdx.x*blockDim.x + threadIdx.x; i<n; i += gridDim.x*blockDim.x){
    u8 d, m;
    if(mode){ d = ((const u8*)done_raw)[i]!=0; m = ((const u8*)main_raw)[i]!=0; }
    else    { d = ((const int*)done_raw)[i]!=0; m = ((const int*)main_raw)[i]!=0; }
    done_u8[i]=d; main_u8[i]=m;
  }
}

__global__ void zero_flags(int* p, int n){
  int i = threadIdx.x;
  if(i<n) p[i]=0;
}

// ---------------- conversions ----------------
__global__ void cvt_f32_bf16(const float* __restrict__ in, u16* __restrict__ out, int n4){
  int i = blockIdx.x*blockDim.x + threadIdx.x;
  if(i < n4){
    float4 v = ((const float4*)in)[i];
    ushort4 o;
    o.x=f2b(v.x); o.y=f2b(v.y); o.z=f2b(v.z); o.w=f2b(v.w);
    ((ushort4*)out)[i]=o;
  }
}

// in [R][C] f32  ->  out [C][R] bf16
__global__ void transpose_to_bf16(const float* __restrict__ in, u16* __restrict__ out, int R, int C){
  __shared__ float tile[64][65];
  int c0 = blockIdx.x*64, r0 = blockIdx.y*64;
  int tx = threadIdx.x & 63, ty = threadIdx.x >> 6;   // 256 threads
  for(int i=ty;i<64;i+=4) tile[i][tx] = in[(size_t)(r0+i)*C + c0 + tx];
  __syncthreads();
  for(int i=ty;i<64;i+=4) out[(size_t)(c0+i)*R + r0 + tx] = f2b(tile[tx][i]);
}

__global__ void init_hsel(const float* __restrict__ h1in, const float* __restrict__ h2in,
                          const u8* __restrict__ mmain, u16* __restrict__ hsel0){
  int i = blockIdx.x*blockDim.x + threadIdx.x;
  if(i < 256*1024){
    int row = i >> 10;
    hsel0[i] = f2b(mmain[row] ? h1in[i] : h2in[i]);
  }
}

// ---------------- phase 1: Zx = x @ Wi + b  (m97-style 128x128 tile) ----------------
template<bool ZF32>
__global__ __launch_bounds__(256) void gemm_zx(const u16* __restrict__ A, const u16* __restrict__ Bt,
                                               const float* __restrict__ bias, void* __restrict__ Cout,
                                               int M, int N, int K){
  __shared__ u16 As[128*32];
  __shared__ u16 Bs[128*32];
  int nbx = N>>7, nby = M>>7;
  int nwg = nbx*nby;                 // 8192, divisible by 8
  int gid = blockIdx.x;
  int per = nwg>>3;
  int g2 = (gid&7)*per + (gid>>3);   // XCD-contiguous remap (bijective: nwg%8==0)
  int tpg = 8*nbx;                   // 8-row supergroup x all cols
  int grp = g2/tpg, w = g2%tpg;
  int brow = grp*8 + (w & 7);
  int bcol = w >> 3;
  int row0 = brow<<7, col0 = bcol<<7;

  int tid=threadIdx.x, wid=tid>>6, lane=tid&63;
  int l15=lane&15, hi=lane>>4;
  int wm=(wid>>1)<<6, wn=(wid&1)<<6;

  f32x4 acc[4][4];
  #pragma unroll
  for(int m=0;m<4;m++)
    #pragma unroll
    for(int n=0;n<4;n++) acc[m][n]=(f32x4){0.f,0.f,0.f,0.f};

  for(int k0=0;k0<K;k0+=32){
    __syncthreads();
    #pragma unroll
    for(int q=0;q<2;q++){
      int cb=q*256+wid*64;
      int ch=cb+lane;
      gl_lds16(A + (size_t)(row0+(ch>>2))*K + k0 + (ch&3)*8, &As[cb*8]);
    }
    #pragma unroll
    for(int q=0;q<2;q++){
      int cb=q*256+wid*64;
      int ch=cb+lane;
      gl_lds16(Bt + (size_t)(col0+(ch>>2))*K + k0 + (ch&3)*8, &Bs[cb*8]);
    }
    __syncthreads();
    s16x8 a[4], b[4];
    #pragma unroll
    for(int m=0;m<4;m++) a[m] = *(const s16x8*)&As[(wm+m*16+l15)*32 + hi*8];
    #pragma unroll
    for(int n=0;n<4;n++) b[n] = *(const s16x8*)&Bs[(wn+n*16+l15)*32 + hi*8];
    #pragma unroll
    for(int m=0;m<4;m++)
      #pragma unroll
      for(int n=0;n<4;n++)
        acc[m][n] = __builtin_amdgcn_mfma_f32_16x16x32_bf16(a[m],b[n],acc[m][n],0,0,0);
  }
  #pragma unroll
  for(int m=0;m<4;m++){
    #pragma unroll
    for(int n=0;n<4;n++){
      #pragma unroll
      for(int j=0;j<4;j++){
        int r = row0+wm+m*16+hi*4+j;
        int c = col0+wn+n*16+l15;
        float v = acc[m][n][j] + bias[c];
        if(ZF32) ((float*)Cout)[(size_t)r*N+c]=v;
        else     ((u16*)Cout)[(size_t)r*N+c]=f2b(v);
      }
    }
  }
}

// ---------------- phase 2: persistent recurrent kernel (plain launch) ----------------
// 256 blocks = 4 row-groups (rg: 64 rows) x 64 col-groups (jg: 16 hcols).
// grid=256 <= 256 CUs, LB(256,1): every CU hosts one block -> all blocks resident
// without cooperative launch. Per-rg chains sync via release/acquire counters.
// Wave (of 4): wm2=wid&1 -> row half; wn2=wid>>1 -> gate pair {2wn2,2wn2+1}.
// Wh^T fragments live in 256 VGPRs per wave, loaded once. States in registers.
template<bool ZF32>
__global__ __launch_bounds__(256,1) void lstm_persist(
    const void* __restrict__ Zx, const u16* __restrict__ Wht,
    u16* __restrict__ hs0, u16* __restrict__ hs1,
    const float* __restrict__ c1i, const float* __restrict__ h1i,
    const float* __restrict__ c2i, const float* __restrict__ h2i,
    const u8* __restrict__ mdone, const u8* __restrict__ mmain,
    float* __restrict__ out, int* __restrict__ ready)
{
  __shared__ u16 As[2][64*64];       // double-buffered h tile, XOR-swizzled
  __shared__ float zbuf[4][64][17];  // gate exchange (pad 17: conflict-free)

  int bid = blockIdx.x;
  int rg = bid & 3, jg = bid >> 2;
  int r0 = rg<<6, j0 = jg<<4;
  int tid = threadIdx.x, wid = tid>>6, lane = tid&63;
  int l15 = lane&15, hi = lane>>4;
  int wm2 = wid&1, wn2 = wid>>1;
  int erow = tid>>4, ecol = tid&15;

  // ---- Wh^T fragments into registers (once) ----
  s16x8 breg[2][32];
  #pragma unroll
  for(int n=0;n<2;n++){
    int g = wn2*2+n;
    const u16* wrow = Wht + ((size_t)(g*1024 + j0 + l15))*1024 + hi*8;
    #pragma unroll
    for(int kk=0;kk<32;kk++)
      breg[n][kk] = *(const s16x8*)(wrow + kk*32);
  }

  // ---- states into registers (once) ----
  float c1r[4], c2r[4], h1r[4], h2r[4];
  #pragma unroll
  for(int e=0;e<4;e++){
    size_t sidx = (size_t)(r0 + e*16 + erow)*1024 + j0 + ecol;
    c1r[e]=c1i[sidx]; c2r[e]=c2i[sidx];
    h1r[e]=h1i[sidx]; h2r[e]=h2i[sidx];
  }

  u16* hb0 = hs0; u16* hb1 = hs1;
  const u16* Zb = (const u16*)Zx;
  const float* Zf = (const float*)Zx;

  for(int t=0;t<128;t++){
    // ---- prefetch Zx + masks for this step (immutable; before the wait) ----
    float zr[4][4];
    u8 md[4], mm[4], mm2[4];
    #pragma unroll
    for(int e=0;e<4;e++){
      int gb = t*256 + r0 + e*16 + erow;
      size_t base = (size_t)gb*4096 + j0 + ecol;
      #pragma unroll
      for(int g=0;g<4;g++){
        if(ZF32) zr[g][e] = Zf[base + g*1024];
        else     zr[g][e] = b2f(Zb[base + g*1024]);
      }
      md[e]=mdone[gb]; mm[e]=mmain[gb];
      mm2[e] = (t<127) ? mmain[gb+256] : (u8)0;
    }

    // ---- wait for previous step's h (per-rg chain); each wave acquires ----
    if(t>0){
      if(lane==0){
        while(__hip_atomic_load(ready+rg, __ATOMIC_ACQUIRE, __HIP_MEMORY_SCOPE_AGENT) < 64*t)
          __builtin_amdgcn_s_sleep(4);
      }
      __syncthreads();
    }

    const u16* hin = (t&1) ? hb1 : hb0;
    u16* hout = (t&1) ? hb0 : hb1;

    auto stageA = [&](int bufi, int w64){
      int k0 = w64<<6;
      {
        int cb = wid*128;
        int ch = cb + lane;
        int r = ch>>3, p = ch&7, l = p ^ (r&7);
        gl_lds16(hin + (size_t)(r0+r)*1024 + k0 + l*8, &As[bufi][cb*8]);
      }
      {
        int cb = wid*128 + 64;
        int ch = cb + lane;
        int r = ch>>3, p = ch&7, l = p ^ (r&7);
        gl_lds16(hin + (size_t)(r0+r)*1024 + k0 + l*8, &As[bufi][cb*8]);
      }
    };

    f32x4 acc[2][2];
    #pragma unroll
    for(int m=0;m<2;m++)
      #pragma unroll
      for(int n=0;n<2;n++) acc[m][n]=(f32x4){0.f,0.f,0.f,0.f};

    stageA(0, 0);
    #pragma unroll
    for(int w=0;w<16;w++){
      __syncthreads();                    // window w staged (vmcnt drained)
      if(w<15) stageA((w+1)&1, w+1);      // issue next window (async)
      #pragma unroll
      for(int ks=0;ks<2;ks++){
        int kk = (w<<1)|ks;               // compile-time (fully unrolled)
        int slot = ks*4 + hi;
        s16x8 a[2];
        #pragma unroll
        for(int m=0;m<2;m++){
          int ar = wm2*32 + m*16 + l15;
          a[m] = *(const s16x8*)&As[w&1][ar*64 + ((slot ^ (ar&7))*8)];
        }
        #pragma unroll
        for(int m=0;m<2;m++)
          #pragma unroll
          for(int n=0;n<2;n++)
            acc[m][n] = __builtin_amdgcn_mfma_f32_16x16x32_bf16(a[m], breg[n][kk], acc[m][n],0,0,0);
      }
    }
    __syncthreads();

    // ---- gate exchange ----
    #pragma unroll
    for(int m=0;m<2;m++)
      #pragma unroll
      for(int n=0;n<2;n++){
        int g = wn2*2+n;
        #pragma unroll
        for(int j=0;j<4;j++){
          int row = wm2*32 + m*16 + hi*4 + j;
          zbuf[g][row][l15] = acc[m][n][j];
        }
      }
    __syncthreads();

    // ---- epilogue: gates, state update, outputs ----
    #pragma unroll
    for(int e=0;e<4;e++){
      int row = e*16 + erow;
      int grow = r0 + row;
      int gb = t*256 + grow;
      float zi = zr[0][e] + zbuf[0][row][ecol];
      float zf = zr[1][e] + zbuf[1][row][ecol];
      float zg = zr[2][e] + zbuf[2][row][ecol];
      float zo = zr[3][e] + zbuf[3][row][ecol];
      bool m_ = mm[e]!=0, d_ = md[e]!=0;
      float co = m_ ? c1r[e] : c2r[e];
      float nc = sigf(zf)*co + sigf(zi)*tanh2(zg);
      float nh = sigf(zo)*tanh2(nc);
      out[(size_t)gb*1024 + j0 + ecol] = nh;
      float n1c = m_?nc:c1r[e], n2c = m_?c2r[e]:nc;
      float n1h = m_?nh:h1r[e], n2h = m_?h2r[e]:nh;
      if(d_){ n1c=0.f; n2c=0.f; n1h=0.f; n2h=0.f; }
      c1r[e]=n1c; c2r[e]=n2c; h1r[e]=n1h; h2r[e]=n2h;
      if(t<127){
        hout[(size_t)grow*1024 + j0 + ecol] = f2b(mm2[e] ? n1h : n2h);
      }
    }
    __threadfence();   // each thread's hout stores agent-visible before the flag
    __syncthreads();
    if(tid==0)
      __hip_atomic_fetch_add(ready+rg, 1, __ATOMIC_RELEASE, __HIP_MEMORY_SCOPE_AGENT);
  }
}

// ---------------- host ----------------
extern "C" void kernel_launch(void* const* d_in, const int* in_sizes, int n_in,
                              void* d_out, int out_size, void* d_ws, size_t ws_size,
                              hipStream_t stream){
  const float* x   = (const float*)d_in[0];
  const float* c1i = (const float*)d_in[1];
  const float* h1i = (const float*)d_in[2];
  const float* c2i = (const float*)d_in[3];
  const float* h2i = (const float*)d_in[4];
  const float* Wi  = (const float*)d_in[5];
  const float* Wh  = (const float*)d_in[6];
  const float* bias= (const float*)d_in[7];
  const void* done_raw = d_in[8];
  const void* main_raw = d_in[9];
  float* out = (float*)d_out;

  char* ws = (char*)d_ws;
  size_t off=0;
  auto alloc=[&](size_t sz)->char*{ char* p = ws+off; off += (sz+255)&~(size_t)255; return p; };

  u16* xb   = (u16*)alloc(33554432ull*2);        // x as bf16 [32768][1024]
  u16* WiT  = (u16*)alloc(4096ull*1024*2);       // Wi^T bf16 [4096][1024]
  u16* WhT  = (u16*)alloc(4096ull*1024*2);       // Wh^T bf16 [4096][1024]
  u16* hs0  = (u16*)alloc(262144ull*2);
  u16* hs1  = (u16*)alloc(262144ull*2);
  u8* dmask = (u8*)alloc(32768);
  u8* mmask = (u8*)alloc(32768);
  int* flag = (int*)alloc(256);
  int* ready= (int*)alloc(256);

  bool zf32 = (off + 536870912ull) <= ws_size;   // Zx fp32 if workspace allows
  void* Zx  = (void*)alloc(zf32 ? 536870912ull : 268435456ull);

  detect_mask_mode<<<1,256,0,stream>>>((const u8*)done_raw, 32768, flag);
  convert_masks<<<64,256,0,stream>>>(done_raw, main_raw, dmask, mmask, 32768, flag);
  cvt_f32_bf16<<<32768,256,0,stream>>>(x, xb, 8388608);
  transpose_to_bf16<<<dim3(64,16),256,0,stream>>>(Wi, WiT, 1024, 4096);
  transpose_to_bf16<<<dim3(64,16),256,0,stream>>>(Wh, WhT, 1024, 4096);
  init_hsel<<<1024,256,0,stream>>>(h1i, h2i, mmask, hs0);
  zero_flags<<<1,64,0,stream>>>(ready, 8);

  if(zf32) gemm_zx<true ><<<8192,256,0,stream>>>(xb, WiT, bias, Zx, 32768, 4096, 1024);
  else     gemm_zx<false><<<8192,256,0,stream>>>(xb, WiT, bias, Zx, 32768, 4096, 1024);

  if(zf32)
    lstm_persist<true ><<<256,256,0,stream>>>(Zx,WhT,hs0,hs1,c1i,h1i,c2i,h2i,dmask,mmask,out,ready);
  else
    lstm_persist<false><<<256,256,0,stream>>>(Zx,WhT,hs0,hs1,c1i,h1i,c2i,h2i,dmask,mmask,out,ready);
}

// Round 4
// 3468.565 us; speedup vs baseline: 1.8177x; 1.8177x over previous
//
#include <hip/hip_runtime.h>
#include <cstdint>
#include <cstddef>

typedef unsigned short u16;
typedef unsigned char u8;
typedef unsigned int u32;

typedef short s16x8 __attribute__((ext_vector_type(8)));
typedef float f32x4 __attribute__((ext_vector_type(4)));

// ---------------- helpers ----------------
__device__ __forceinline__ float b2f(u16 h){ u32 u = ((u32)h)<<16; float f; __builtin_memcpy(&f,&u,4); return f; }
__device__ __forceinline__ u16 f2b(float x){ u32 u; __builtin_memcpy(&u,&x,4); u += 0x7fffu + ((u>>16)&1u); return (u16)(u>>16); }
__device__ __forceinline__ float sigf(float x){ return 1.f/(1.f+__expf(-x)); }
__device__ __forceinline__ float tanh2(float x){
  float ax=fabsf(x); float e=__expf(-2.f*ax); float r=(1.f-e)/(1.f+e); return x<0.f? -r : r;
}

typedef __attribute__((address_space(1))) const void gvoid_t;
typedef __attribute__((address_space(3))) void lvoid_t;
__device__ __forceinline__ void gl_lds16(const u16* src, u16* dst){
  __builtin_amdgcn_global_load_lds((gvoid_t*)src, (lvoid_t*)dst, 16, 0, 0);
}

// coherent (write-through to coherence point) stores — no L2 dirtying
__device__ __forceinline__ void st_u16_coh(u16* p, u16 v){
  asm volatile("global_store_short %0, %1, off sc0 sc1" :: "v"(p), "v"((u32)v) : "memory");
}
__device__ __forceinline__ void st_f32_coh(float* p, float v){
  asm volatile("global_store_dword %0, %1, off sc0 sc1" :: "v"(p), "v"(v) : "memory");
}
// non-rematerializable 16B load (pins result in VGPRs)
__device__ __forceinline__ s16x8 gload16(const u16* p){
  s16x8 r;
  asm volatile("global_load_dwordx4 %0, %1, off" : "=v"(r) : "v"(p) : "memory");
  return r;
}

// ---------------- mask dtype detection + canonicalization ----------------
__global__ void detect_mask_mode(const u8* raw, int n, int* flag){
  __shared__ int cnt;
  int tid = threadIdx.x;
  if(tid==0) cnt=0;
  __syncthreads();
  int c=0;
  for(int i=tid;i<n;i+=blockDim.x) c += (raw[i]!=0);
  atomicAdd(&cnt, c);
  __syncthreads();
  if(tid==0) *flag = (cnt > (n>>2)) ? 1 : 0;  // 1 => byte-per-element layout
}

__global__ void convert_masks(const void* done_raw, const void* main_raw, u8* done_u8, u8* main_u8, int n, const int* flag){
  int mode = *flag;
  for(int i = blockIdx.x*blockDim.x + threadIdx.x; i<n; i += gridDim.x*blockDim.x){
    u8 d, m;
    if(mode){ d = ((const u8*)done_raw)[i]!=0; m = ((const u8*)main_raw)[i]!=0; }
    else    { d = ((const int*)done_raw)[i]!=0; m = ((const int*)main_raw)[i]!=0; }
    done_u8[i]=d; main_u8[i]=m;
  }
}

__global__ void zero_flags(int* p, int n){
  int i = threadIdx.x;
  if(i<n) p[i]=0;
}

// ---------------- conversions ----------------
__global__ void cvt_f32_bf16(const float* __restrict__ in, u16* __restrict__ out, int n4){
  int i = blockIdx.x*blockDim.x + threadIdx.x;
  if(i < n4){
    float4 v = ((const float4*)in)[i];
    ushort4 o;
    o.x=f2b(v.x); o.y=f2b(v.y); o.z=f2b(v.z); o.w=f2b(v.w);
    ((ushort4*)out)[i]=o;
  }
}

// in [R][C] f32  ->  out [C][R] bf16
__global__ void transpose_to_bf16(const float* __restrict__ in, u16* __restrict__ out, int R, int C){
  __shared__ float tile[64][65];
  int c0 = blockIdx.x*64, r0 = blockIdx.y*64;
  int tx = threadIdx.x & 63, ty = threadIdx.x >> 6;   // 256 threads
  for(int i=ty;i<64;i+=4) tile[i][tx] = in[(size_t)(r0+i)*C + c0 + tx];
  __syncthreads();
  for(int i=ty;i<64;i+=4) out[(size_t)(c0+i)*R + r0 + tx] = f2b(tile[tx][i]);
}

__global__ void init_hsel(const float* __restrict__ h1in, const float* __restrict__ h2in,
                          const u8* __restrict__ mmain, u16* __restrict__ hsel0){
  int i = blockIdx.x*blockDim.x + threadIdx.x;
  if(i < 256*1024){
    int row = i >> 10;
    hsel0[i] = f2b(mmain[row] ? h1in[i] : h2in[i]);
  }
}

// ---------------- phase 1: Zx = x @ Wi + b  (m97-style 128x128 tile) ----------------
template<bool ZF32>
__global__ __launch_bounds__(256) void gemm_zx(const u16* __restrict__ A, const u16* __restrict__ Bt,
                                               const float* __restrict__ bias, void* __restrict__ Cout,
                                               int M, int N, int K){
  __shared__ u16 As[128*32];
  __shared__ u16 Bs[128*32];
  int nbx = N>>7, nby = M>>7;
  int nwg = nbx*nby;                 // 8192, divisible by 8
  int gid = blockIdx.x;
  int per = nwg>>3;
  int g2 = (gid&7)*per + (gid>>3);   // XCD-contiguous remap (bijective: nwg%8==0)
  int tpg = 8*nbx;                   // 8-row supergroup x all cols
  int grp = g2/tpg, w = g2%tpg;
  int brow = grp*8 + (w & 7);
  int bcol = w >> 3;
  int row0 = brow<<7, col0 = bcol<<7;

  int tid=threadIdx.x, wid=tid>>6, lane=tid&63;
  int l15=lane&15, hi=lane>>4;
  int wm=(wid>>1)<<6, wn=(wid&1)<<6;

  f32x4 acc[4][4];
  #pragma unroll
  for(int m=0;m<4;m++)
    #pragma unroll
    for(int n=0;n<4;n++) acc[m][n]=(f32x4){0.f,0.f,0.f,0.f};

  for(int k0=0;k0<K;k0+=32){
    __syncthreads();
    #pragma unroll
    for(int q=0;q<2;q++){
      int cb=q*256+wid*64;
      int ch=cb+lane;
      gl_lds16(A + (size_t)(row0+(ch>>2))*K + k0 + (ch&3)*8, &As[cb*8]);
    }
    #pragma unroll
    for(int q=0;q<2;q++){
      int cb=q*256+wid*64;
      int ch=cb+lane;
      gl_lds16(Bt + (size_t)(col0+(ch>>2))*K + k0 + (ch&3)*8, &Bs[cb*8]);
    }
    __syncthreads();
    s16x8 a[4], b[4];
    #pragma unroll
    for(int m=0;m<4;m++) a[m] = *(const s16x8*)&As[(wm+m*16+l15)*32 + hi*8];
    #pragma unroll
    for(int n=0;n<4;n++) b[n] = *(const s16x8*)&Bs[(wn+n*16+l15)*32 + hi*8];
    #pragma unroll
    for(int m=0;m<4;m++)
      #pragma unroll
      for(int n=0;n<4;n++)
        acc[m][n] = __builtin_amdgcn_mfma_f32_16x16x32_bf16(a[m],b[n],acc[m][n],0,0,0);
  }
  #pragma unroll
  for(int m=0;m<4;m++){
    #pragma unroll
    for(int n=0;n<4;n++){
      #pragma unroll
      for(int j=0;j<4;j++){
        int r = row0+wm+m*16+hi*4+j;
        int c = col0+wn+n*16+l15;
        float v = acc[m][n][j] + bias[c];
        if(ZF32) ((float*)Cout)[(size_t)r*N+c]=v;
        else     ((u16*)Cout)[(size_t)r*N+c]=f2b(v);
      }
    }
  }
}

// ---------------- phase 2: persistent recurrent kernel ----------------
// 256 blocks x 512 threads (8 waves). rg=bid&3 (64 rows), jg=bid>>2 (16 hcols).
// Default dispatch maps bid%8 -> XCD, so rg == XCD&3: each rg chain lives on 2 XCDs
// and the per-step h-tile L2 refill is shared by 32 blocks per XCD.
// Wave wid: gate = wid>>1, row-half rh = wid&1. breg (Wh^T frags) = 128 VGPR/wave,
// pinned via asm loads. States in registers. No L2 writeback anywhere in the loop:
// producers write h/out with sc0sc1 write-through stores + relaxed atomic flag;
// consumers spin relaxed then acquire-fence (buffer_inv) and re-read through L2.
template<bool ZF32>
__global__ __launch_bounds__(512,2) void lstm_persist(
    const void* __restrict__ Zx, const u16* __restrict__ Wht,
    u16* __restrict__ hs0, u16* __restrict__ hs1,
    const float* __restrict__ c1i, const float* __restrict__ h1i,
    const float* __restrict__ c2i, const float* __restrict__ h2i,
    const u8* __restrict__ mdone, const u8* __restrict__ mmain,
    float* __restrict__ out, int* __restrict__ ready)
{
  __shared__ u16 As[32768];    // 64 KB: [16 kkl][4 hi][64 rows][8 u16] per half
  float* zbuf = (float*)As;    // aliased after MFMA phase (barrier-separated)

  const int bid = blockIdx.x;
  const int rg = bid & 3, jg = bid >> 2;
  const int r0 = rg << 6, j0 = jg << 4;
  const int tid = threadIdx.x, wid = tid >> 6, lane = tid & 63;
  const int l15 = lane & 15, hi = lane >> 4;
  const int gate = wid >> 1, rh = wid & 1;
  const int erow = (tid >> 4) & 31, ecol = tid & 15;

  // ---- Wh^T fragments for this wave's gate: 32 x s16x8 = 128 VGPRs ----
  s16x8 breg[32];
  {
    const u16* wp = Wht + ((size_t)(gate*1024 + j0 + l15))*1024 + (size_t)hi*8;
    #pragma unroll
    for(int kk=0;kk<32;kk++) breg[kk] = gload16(wp + kk*32);
    asm volatile("s_waitcnt vmcnt(0)" ::: "memory");
    __builtin_amdgcn_sched_barrier(0);
  }

  // ---- states into registers (once) ----
  float c1r[2],c2r[2],h1r[2],h2r[2];
  #pragma unroll
  for(int e=0;e<2;e++){
    size_t sidx = (size_t)(r0 + e*32 + erow)*1024 + j0 + ecol;
    c1r[e]=c1i[sidx]; c2r[e]=c2i[sidx]; h1r[e]=h1i[sidx]; h2r[e]=h2i[sidx];
  }

  const u16* Zb = (const u16*)Zx;
  const float* Zf = (const float*)Zx;
  int* flag = ready + rg*16;   // 64B-padded counters

  for(int t=0;t<128;t++){
    // ---- prefetch step-local immutable inputs before the chain wait ----
    float zr[4][2]; u8 md[2], mm[2], mm2[2];
    #pragma unroll
    for(int e=0;e<2;e++){
      int gb = t*256 + r0 + e*32 + erow;
      size_t base = (size_t)gb*4096 + j0 + ecol;
      #pragma unroll
      for(int g=0; g<4; g++)
        zr[g][e] = ZF32 ? Zf[base + g*1024] : b2f(Zb[base + g*1024]);
      md[e]=mdone[gb]; mm[e]=mmain[gb];
      mm2[e] = (t<127) ? mmain[gb+256] : (u8)0;
    }
    __builtin_amdgcn_sched_barrier(0);

    // ---- wait for previous step (per-rg chain), then cheap acquire ----
    if(t>0){
      if(lane==0){
        while(__hip_atomic_load(flag, __ATOMIC_RELAXED, __HIP_MEMORY_SCOPE_AGENT) < 64*t)
          __builtin_amdgcn_s_sleep(2);
      }
      __builtin_amdgcn_fence(__ATOMIC_ACQUIRE, "agent");  // buffer_inv; no writeback
    }

    const u16* hin = (t&1) ? hs1 : hs0;
    u16* hout = (t&1) ? hs0 : hs1;

    f32x4 acc[2];
    acc[0]=(f32x4){0.f,0.f,0.f,0.f}; acc[1]=(f32x4){0.f,0.f,0.f,0.f};

    #pragma unroll
    for(int hf=0; hf<2; hf++){
      __syncthreads();     // previous readers of As done (epilogue zbuf / prior half)
      #pragma unroll
      for(int q=0;q<8;q++){
        int sl = wid*8 + q;              // slice 0..63 = [kkl 0..15][shi 0..3]
        int kkl = sl>>2, shi = sl&3;
        gl_lds16(hin + (size_t)(r0+lane)*1024 + (hf*16+kkl)*32 + shi*8,
                 &As[sl*512]);           // linear 1KB dest per instruction
      }
      __syncthreads();     // staging landed (vmcnt drained by barrier)
      #pragma unroll
      for(int kkl=0;kkl<16;kkl++){
        int rbase = kkl*2048 + hi*512 + (rh*32 + l15)*8;
        s16x8 a0 = *(const s16x8*)&As[rbase];
        s16x8 a1 = *(const s16x8*)&As[rbase + 128];   // +16 rows
        acc[0] = __builtin_amdgcn_mfma_f32_16x16x32_bf16(a0, breg[hf*16+kkl], acc[0], 0,0,0);
        acc[1] = __builtin_amdgcn_mfma_f32_16x16x32_bf16(a1, breg[hf*16+kkl], acc[1], 0,0,0);
      }
    }
    __syncthreads();       // all MFMA LDS reads done -> alias As as zbuf

    // ---- gate exchange (zbuf[gate][row][17]) ----
    #pragma unroll
    for(int m=0;m<2;m++)
      #pragma unroll
      for(int j=0;j<4;j++){
        int row = rh*32 + m*16 + hi*4 + j;
        zbuf[(gate*64 + row)*17 + l15] = acc[m][j];
      }
    __syncthreads();

    // ---- epilogue: gates, state update, coherent stores ----
    #pragma unroll
    for(int e=0;e<2;e++){
      int row = e*32 + erow;
      int grow = r0 + row;
      int gb = t*256 + grow;
      float zi  = zr[0][e] + zbuf[(0*64+row)*17 + ecol];
      float zf_ = zr[1][e] + zbuf[(1*64+row)*17 + ecol];
      float zg  = zr[2][e] + zbuf[(2*64+row)*17 + ecol];
      float zo  = zr[3][e] + zbuf[(3*64+row)*17 + ecol];
      bool m_ = mm[e]!=0, d_ = md[e]!=0;
      float co = m_ ? c1r[e] : c2r[e];
      float nc = sigf(zf_)*co + sigf(zi)*tanh2(zg);
      float nh = sigf(zo)*tanh2(nc);
      st_f32_coh(&out[(size_t)gb*1024 + j0 + ecol], nh);
      float n1c = m_?nc:c1r[e], n2c = m_?c2r[e]:nc;
      float n1h = m_?nh:h1r[e], n2h = m_?h2r[e]:nh;
      if(d_){ n1c=0.f; n2c=0.f; n1h=0.f; n2h=0.f; }
      c1r[e]=n1c; c2r[e]=n2c; h1r[e]=n1h; h2r[e]=n2h;
      if(t<127)
        st_u16_coh(&hout[(size_t)grow*1024 + j0 + ecol], f2b(mm2[e] ? n1h : n2h));
    }
    asm volatile("s_waitcnt vmcnt(0)" ::: "memory");   // stores at coherence point
    __syncthreads();
    if(tid==0)
      __hip_atomic_fetch_add(flag, 1, __ATOMIC_RELAXED, __HIP_MEMORY_SCOPE_AGENT);
  }
}

// ---------------- host ----------------
extern "C" void kernel_launch(void* const* d_in, const int* in_sizes, int n_in,
                              void* d_out, int out_size, void* d_ws, size_t ws_size,
                              hipStream_t stream){
  const float* x   = (const float*)d_in[0];
  const float* c1i = (const float*)d_in[1];
  const float* h1i = (const float*)d_in[2];
  const float* c2i = (const float*)d_in[3];
  const float* h2i = (const float*)d_in[4];
  const float* Wi  = (const float*)d_in[5];
  const float* Wh  = (const float*)d_in[6];
  const float* bias= (const float*)d_in[7];
  const void* done_raw = d_in[8];
  const void* main_raw = d_in[9];
  float* out = (float*)d_out;

  char* ws = (char*)d_ws;
  size_t off=0;
  auto alloc=[&](size_t sz)->char*{ char* p = ws+off; off += (sz+255)&~(size_t)255; return p; };

  u16* xb   = (u16*)alloc(33554432ull*2);        // x as bf16 [32768][1024]
  u16* WiT  = (u16*)alloc(4096ull*1024*2);       // Wi^T bf16 [4096][1024]
  u16* WhT  = (u16*)alloc(4096ull*1024*2);       // Wh^T bf16 [4096][1024]
  u16* hs0  = (u16*)alloc(262144ull*2);
  u16* hs1  = (u16*)alloc(262144ull*2);
  u8* dmask = (u8*)alloc(32768);
  u8* mmask = (u8*)alloc(32768);
  int* flag = (int*)alloc(256);
  int* ready= (int*)alloc(256);

  bool zf32 = (off + 536870912ull) <= ws_size;   // Zx fp32 if workspace allows
  void* Zx  = (void*)alloc(zf32 ? 536870912ull : 268435456ull);

  detect_mask_mode<<<1,256,0,stream>>>((const u8*)done_raw, 32768, flag);
  convert_masks<<<64,256,0,stream>>>(done_raw, main_raw, dmask, mmask, 32768, flag);
  cvt_f32_bf16<<<32768,256,0,stream>>>(x, xb, 8388608);
  transpose_to_bf16<<<dim3(64,16),256,0,stream>>>(Wi, WiT, 1024, 4096);
  transpose_to_bf16<<<dim3(64,16),256,0,stream>>>(Wh, WhT, 1024, 4096);
  init_hsel<<<1024,256,0,stream>>>(h1i, h2i, mmask, hs0);
  zero_flags<<<1,64,0,stream>>>(ready, 64);

  if(zf32) gemm_zx<true ><<<8192,256,0,stream>>>(xb, WiT, bias, Zx, 32768, 4096, 1024);
  else     gemm_zx<false><<<8192,256,0,stream>>>(xb, WiT, bias, Zx, 32768, 4096, 1024);

  if(zf32)
    lstm_persist<true ><<<256,512,0,stream>>>(Zx,WhT,hs0,hs1,c1i,h1i,c2i,h2i,dmask,mmask,out,ready);
  else
    lstm_persist<false><<<256,512,0,stream>>>(Zx,WhT,hs0,hs1,c1i,h1i,c2i,h2i,dmask,mmask,out,ready);
}

// Round 5
// 1127.764 us; speedup vs baseline: 5.5907x; 3.0756x over previous
//
#include <hip/hip_runtime.h>
#include <cstdint>
#include <cstddef>

typedef unsigned short u16;
typedef unsigned char u8;
typedef unsigned int u32;

typedef short s16x8 __attribute__((ext_vector_type(8)));
typedef float f32x4 __attribute__((ext_vector_type(4)));

// ---------------- helpers ----------------
__device__ __forceinline__ float b2f(u16 h){ u32 u = ((u32)h)<<16; float f; __builtin_memcpy(&f,&u,4); return f; }
__device__ __forceinline__ u16 f2b(float x){ u32 u; __builtin_memcpy(&u,&x,4); u += 0x7fffu + ((u>>16)&1u); return (u16)(u>>16); }
__device__ __forceinline__ float sigf(float x){ return 1.f/(1.f+__expf(-x)); }
__device__ __forceinline__ float tanh2(float x){
  float ax=fabsf(x); float e=__expf(-2.f*ax); float r=(1.f-e)/(1.f+e); return x<0.f? -r : r;
}

typedef __attribute__((address_space(1))) const void gvoid_t;
typedef __attribute__((address_space(3))) void lvoid_t;
__device__ __forceinline__ void gl_lds16(const u16* src, u16* dst){
  __builtin_amdgcn_global_load_lds((gvoid_t*)src, (lvoid_t*)dst, 16, 0, 0);
}

// coherent write-through store (to coherence point; no L2 dirtying)
__device__ __forceinline__ void st_u16_coh(u16* p, u16 v){
  asm volatile("global_store_short %0, %1, off sc0 sc1" :: "v"(p), "v"((u32)v) : "memory");
}
__device__ __forceinline__ void st_f32_coh(float* p, float v){
  asm volatile("global_store_dword %0, %1, off sc0 sc1" :: "v"(p), "v"(v) : "memory");
}
// pinned (non-rematerializable) 16B loads
__device__ __forceinline__ s16x8 gload16(const u16* p){
  s16x8 r;
  asm volatile("global_load_dwordx4 %0, %1, off" : "=v"(r) : "v"(p) : "memory");
  return r;
}
// coherent 16B load: reads at coherence point (never stale; no invalidate needed)
__device__ __forceinline__ s16x8 gload16_coh(const u16* p){
  s16x8 r;
  asm volatile("global_load_dwordx4 %0, %1, off sc0 sc1" : "=v"(r) : "v"(p) : "memory");
  return r;
}

// ---------------- mask dtype detection + canonicalization ----------------
__global__ void detect_mask_mode(const u8* raw, int n, int* flag){
  __shared__ int cnt;
  int tid = threadIdx.x;
  if(tid==0) cnt=0;
  __syncthreads();
  int c=0;
  for(int i=tid;i<n;i+=blockDim.x) c += (raw[i]!=0);
  atomicAdd(&cnt, c);
  __syncthreads();
  if(tid==0) *flag = (cnt > (n>>2)) ? 1 : 0;  // 1 => byte-per-element layout
}

__global__ void convert_masks(const void* done_raw, const void* main_raw, u8* done_u8, u8* main_u8, int n, const int* flag){
  int mode = *flag;
  for(int i = blockIdx.x*blockDim.x + threadIdx.x; i<n; i += gridDim.x*blockDim.x){
    u8 d, m;
    if(mode){ d = ((const u8*)done_raw)[i]!=0; m = ((const u8*)main_raw)[i]!=0; }
    else    { d = ((const int*)done_raw)[i]!=0; m = ((const int*)main_raw)[i]!=0; }
    done_u8[i]=d; main_u8[i]=m;
  }
}

__global__ void zero_flags(int* p, int n){
  int i = threadIdx.x;
  if(i<n) p[i]=0;
}

// ---------------- conversions ----------------
__global__ void cvt_f32_bf16(const float* __restrict__ in, u16* __restrict__ out, int n4){
  int i = blockIdx.x*blockDim.x + threadIdx.x;
  if(i < n4){
    float4 v = ((const float4*)in)[i];
    ushort4 o;
    o.x=f2b(v.x); o.y=f2b(v.y); o.z=f2b(v.z); o.w=f2b(v.w);
    ((ushort4*)out)[i]=o;
  }
}

// in [R][C] f32  ->  out [C][R] bf16
__global__ void transpose_to_bf16(const float* __restrict__ in, u16* __restrict__ out, int R, int C){
  __shared__ float tile[64][65];
  int c0 = blockIdx.x*64, r0 = blockIdx.y*64;
  int tx = threadIdx.x & 63, ty = threadIdx.x >> 6;   // 256 threads
  for(int i=ty;i<64;i+=4) tile[i][tx] = in[(size_t)(r0+i)*C + c0 + tx];
  __syncthreads();
  for(int i=ty;i<64;i+=4) out[(size_t)(c0+i)*R + r0 + tx] = f2b(tile[tx][i]);
}

__global__ void init_hsel(const float* __restrict__ h1in, const float* __restrict__ h2in,
                          const u8* __restrict__ mmain, u16* __restrict__ hsel0){
  int i = blockIdx.x*blockDim.x + threadIdx.x;
  if(i < 256*1024){
    int row = i >> 10;
    hsel0[i] = f2b(mmain[row] ? h1in[i] : h2in[i]);
  }
}

// ---------------- phase 1: Zx = x @ Wi + b  (m97-style 128x128 tile) ----------------
template<bool ZF32>
__global__ __launch_bounds__(256) void gemm_zx(const u16* __restrict__ A, const u16* __restrict__ Bt,
                                               const float* __restrict__ bias, void* __restrict__ Cout,
                                               int M, int N, int K){
  __shared__ u16 As[128*32];
  __shared__ u16 Bs[128*32];
  int nbx = N>>7, nby = M>>7;
  int nwg = nbx*nby;                 // 8192, divisible by 8
  int gid = blockIdx.x;
  int per = nwg>>3;
  int g2 = (gid&7)*per + (gid>>3);   // XCD-contiguous remap (bijective: nwg%8==0)
  int tpg = 8*nbx;                   // 8-row supergroup x all cols
  int grp = g2/tpg, w = g2%tpg;
  int brow = grp*8 + (w & 7);
  int bcol = w >> 3;
  int row0 = brow<<7, col0 = bcol<<7;

  int tid=threadIdx.x, wid=tid>>6, lane=tid&63;
  int l15=lane&15, hi=lane>>4;
  int wm=(wid>>1)<<6, wn=(wid&1)<<6;

  f32x4 acc[4][4];
  #pragma unroll
  for(int m=0;m<4;m++)
    #pragma unroll
    for(int n=0;n<4;n++) acc[m][n]=(f32x4){0.f,0.f,0.f,0.f};

  for(int k0=0;k0<K;k0+=32){
    __syncthreads();
    #pragma unroll
    for(int q=0;q<2;q++){
      int cb=q*256+wid*64;
      int ch=cb+lane;
      gl_lds16(A + (size_t)(row0+(ch>>2))*K + k0 + (ch&3)*8, &As[cb*8]);
    }
    #pragma unroll
    for(int q=0;q<2;q++){
      int cb=q*256+wid*64;
      int ch=cb+lane;
      gl_lds16(Bt + (size_t)(col0+(ch>>2))*K + k0 + (ch&3)*8, &Bs[cb*8]);
    }
    __syncthreads();
    s16x8 a[4], b[4];
    #pragma unroll
    for(int m=0;m<4;m++) a[m] = *(const s16x8*)&As[(wm+m*16+l15)*32 + hi*8];
    #pragma unroll
    for(int n=0;n<4;n++) b[n] = *(const s16x8*)&Bs[(wn+n*16+l15)*32 + hi*8];
    #pragma unroll
    for(int m=0;m<4;m++)
      #pragma unroll
      for(int n=0;n<4;n++)
        acc[m][n] = __builtin_amdgcn_mfma_f32_16x16x32_bf16(a[m],b[n],acc[m][n],0,0,0);
  }
  #pragma unroll
  for(int m=0;m<4;m++){
    #pragma unroll
    for(int n=0;n<4;n++){
      #pragma unroll
      for(int j=0;j<4;j++){
        int r = row0+wm+m*16+hi*4+j;
        int c = col0+wn+n*16+l15;
        float v = acc[m][n][j] + bias[c];
        if(ZF32) ((float*)Cout)[(size_t)r*N+c]=v;
        else     ((u16*)Cout)[(size_t)r*N+c]=f2b(v);
      }
    }
  }
}

// ---------------- phase 2: persistent recurrent kernel ----------------
// 256 blocks x 512 threads (8 waves), 1 block/CU. rg=bid&7 (32 rows, aligns
// rg<->XCD under round-robin dispatch), jg=bid>>3 (32 hcols). Wave wid:
// gate=wid>>1, nh=wid&1 (16-col half). breg (Wh^T frags) = 128 VGPR/wave,
// pinned via asm loads; amdgpu_waves_per_eu(2,2) caps 2 waves/SIMD so the
// allocator has the full 256-VGPR budget (R4's spill fix). States in regs.
// Sync: producer sc0sc1 write-through h stores + vmcnt(0) + relaxed flag;
// consumer spins relaxed then reads h at the coherence point with sc0sc1
// loads into regs and ds_writes a swizzled LDS tile. NO cache invalidates.
template<bool ZF32>
__global__ __launch_bounds__(512) __attribute__((amdgpu_waves_per_eu(2,2)))
void lstm_persist(
    const void* __restrict__ Zx, const u16* __restrict__ Wht,
    u16* __restrict__ hs0, u16* __restrict__ hs1,
    const float* __restrict__ c1i, const float* __restrict__ h1i,
    const float* __restrict__ c2i, const float* __restrict__ h2i,
    const u8* __restrict__ mdone, const u8* __restrict__ mmain,
    float* __restrict__ out, int* __restrict__ ready)
{
  __shared__ u16 As[32768];     // 64 KB: 128 chunks x [32 rows x 16B], XOR-swizzled
  float* zbuf = (float*)As;     // aliased after MFMA (barrier-separated)

  const int bid = blockIdx.x;
  const int rg = bid & 7, jg = bid >> 3;
  const int r0 = rg << 5, j0 = jg << 5;
  const int tid = threadIdx.x, wid = tid >> 6, lane = tid & 63;
  const int l15 = lane & 15, hi = lane >> 4;
  const int gate = wid >> 1, nh = wid & 1;
  const int srow = tid >> 4, sc16 = tid & 15;   // staging: row 0..31, col16 0..15
  const int erow = tid >> 5, ecol = tid & 31;   // epilogue: 16 row-pairs x 32 cols

  // ---- Wh^T fragments for this wave's 16 gate-cols: 32 x s16x8 = 128 VGPRs ----
  s16x8 breg[32];
  {
    const u16* wp = Wht + ((size_t)(gate*1024 + j0 + nh*16 + l15))*1024 + (size_t)hi*8;
    #pragma unroll
    for(int kk=0;kk<32;kk++) breg[kk] = gload16(wp + kk*32);
    asm volatile("s_waitcnt vmcnt(0)" ::: "memory");
    __builtin_amdgcn_sched_barrier(0);
  }

  // ---- states into registers (thread-stationary across all 128 steps) ----
  float c1r[2],c2r[2],h1r[2],h2r[2];
  #pragma unroll
  for(int e=0;e<2;e++){
    size_t sidx = (size_t)(r0 + e*16 + erow)*1024 + j0 + ecol;
    c1r[e]=c1i[sidx]; c2r[e]=c2i[sidx]; h1r[e]=h1i[sidx]; h2r[e]=h2i[sidx];
  }

  const u16* Zb = (const u16*)Zx;
  const float* Zf = (const float*)Zx;
  int* flag = ready + rg*32;    // 128B-spaced per-rg counters

  for(int t=0;t<128;t++){
    // ---- prefetch step-local immutable inputs (cached; L2 stays warm) ----
    float zr[4][2]; u8 md[2], mm[2], mm2[2];
    #pragma unroll
    for(int e=0;e<2;e++){
      int gb = t*256 + r0 + e*16 + erow;
      size_t base = (size_t)gb*4096 + j0 + ecol;
      #pragma unroll
      for(int g=0; g<4; g++)
        zr[g][e] = ZF32 ? Zf[base + g*1024] : b2f(Zb[base + g*1024]);
      md[e]=mdone[gb]; mm[e]=mmain[gb];
      mm2[e] = (t<127) ? mmain[gb+256] : (u8)0;
    }

    // ---- chain wait (single spinner; others park at the barrier) ----
    if(t>0 && tid==0){
      while(__hip_atomic_load(flag, __ATOMIC_RELAXED, __HIP_MEMORY_SCOPE_AGENT) < 32*t)
        __builtin_amdgcn_s_sleep(1);
    }
    __syncthreads();
    __builtin_amdgcn_sched_barrier(0);

    const u16* hin = (t&1) ? hs1 : hs0;
    u16* hout = (t&1) ? hs0 : hs1;

    // ---- stage h tile: 8 coherent 16B loads/thread -> swizzled LDS ----
    {
      const u16* hrow = hin + (size_t)(r0+srow)*1024;
      s16x8 v[8];
      #pragma unroll
      for(int kc=0;kc<8;kc++) v[kc] = gload16_coh(hrow + (kc*16+sc16)*8);
      asm volatile("s_waitcnt vmcnt(0)" ::: "memory");
      #pragma unroll
      for(int kc=0;kc<8;kc++){
        int chunk = kc*16+sc16;                       // 0..127 (8 bf16 of K each)
        *(s16x8*)&As[chunk*256 + ((srow ^ (chunk&7))<<3)] = v[kc];
      }
    }
    __syncthreads();   // tile staged

    // ---- recurrent GEMM: 64 MFMA/wave, B from registers ----
    f32x4 acc[2];
    acc[0]=(f32x4){0.f,0.f,0.f,0.f}; acc[1]=(f32x4){0.f,0.f,0.f,0.f};
    #pragma unroll
    for(int kk=0;kk<32;kk++){
      int c0 = kk*4 + hi;
      s16x8 a0 = *(const s16x8*)&As[c0*256 + ((l15      ^ (c0&7))<<3)];
      s16x8 a1 = *(const s16x8*)&As[c0*256 + (((16+l15) ^ (c0&7))<<3)];
      acc[0] = __builtin_amdgcn_mfma_f32_16x16x32_bf16(a0, breg[kk], acc[0], 0,0,0);
      acc[1] = __builtin_amdgcn_mfma_f32_16x16x32_bf16(a1, breg[kk], acc[1], 0,0,0);
    }
    __syncthreads();   // all LDS reads done -> alias As as zbuf

    // ---- gate exchange: zbuf[gate][row(32)][33] ----
    #pragma unroll
    for(int m=0;m<2;m++)
      #pragma unroll
      for(int j=0;j<4;j++){
        int row = m*16 + hi*4 + j;
        zbuf[(gate*32 + row)*33 + nh*16 + l15] = acc[m][j];
      }
    __syncthreads();

    // ---- epilogue: gates, state update; h stores first (critical path) ----
    float nhv[2];
    #pragma unroll
    for(int e=0;e<2;e++){
      int row = e*16 + erow;
      float zi  = zr[0][e] + zbuf[(0*32+row)*33 + ecol];
      float zf_ = zr[1][e] + zbuf[(1*32+row)*33 + ecol];
      float zg  = zr[2][e] + zbuf[(2*32+row)*33 + ecol];
      float zo  = zr[3][e] + zbuf[(3*32+row)*33 + ecol];
      bool m_ = mm[e]!=0, d_ = md[e]!=0;
      float co = m_ ? c1r[e] : c2r[e];
      float nc = sigf(zf_)*co + sigf(zi)*tanh2(zg);
      float nhx = sigf(zo)*tanh2(nc);
      nhv[e] = nhx;
      float n1c = m_?nc:c1r[e], n2c = m_?c2r[e]:nc;
      float n1h = m_?nhx:h1r[e], n2h = m_?h2r[e]:nhx;
      if(d_){ n1c=0.f; n2c=0.f; n1h=0.f; n2h=0.f; }
      c1r[e]=n1c; c2r[e]=n2c; h1r[e]=n1h; h2r[e]=n2h;
      if(t<127)
        st_u16_coh(&hout[(size_t)(r0+row)*1024 + j0 + ecol], f2b(mm2[e] ? n1h : n2h));
    }
    asm volatile("s_waitcnt vmcnt(0)" ::: "memory");   // h at coherence point
    __syncthreads();
    if(t<127 && tid==0)
      __hip_atomic_fetch_add(flag, 1, __ATOMIC_RELAXED, __HIP_MEMORY_SCOPE_AGENT);

    // ---- out store off the critical path (drains during next spin) ----
    #pragma unroll
    for(int e=0;e<2;e++){
      int gb = t*256 + r0 + e*16 + erow;
      st_f32_coh(&out[(size_t)gb*1024 + j0 + ecol], nhv[e]);
    }
  }
}

// ---------------- host ----------------
extern "C" void kernel_launch(void* const* d_in, const int* in_sizes, int n_in,
                              void* d_out, int out_size, void* d_ws, size_t ws_size,
                              hipStream_t stream){
  const float* x   = (const float*)d_in[0];
  const float* c1i = (const float*)d_in[1];
  const float* h1i = (const float*)d_in[2];
  const float* c2i = (const float*)d_in[3];
  const float* h2i = (const float*)d_in[4];
  const float* Wi  = (const float*)d_in[5];
  const float* Wh  = (const float*)d_in[6];
  const float* bias= (const float*)d_in[7];
  const void* done_raw = d_in[8];
  const void* main_raw = d_in[9];
  float* out = (float*)d_out;

  char* ws = (char*)d_ws;
  size_t off=0;
  auto alloc=[&](size_t sz)->char*{ char* p = ws+off; off += (sz+255)&~(size_t)255; return p; };

  u16* xb   = (u16*)alloc(33554432ull*2);        // x as bf16 [32768][1024]
  u16* WiT  = (u16*)alloc(4096ull*1024*2);       // Wi^T bf16 [4096][1024]
  u16* WhT  = (u16*)alloc(4096ull*1024*2);       // Wh^T bf16 [4096][1024]
  u16* hs0  = (u16*)alloc(262144ull*2);
  u16* hs1  = (u16*)alloc(262144ull*2);
  u8* dmask = (u8*)alloc(32768);
  u8* mmask = (u8*)alloc(32768);
  int* flag = (int*)alloc(256);
  int* ready= (int*)alloc(1024);

  bool zf32 = (off + 536870912ull) <= ws_size;   // Zx fp32 if workspace allows
  void* Zx  = (void*)alloc(zf32 ? 536870912ull : 268435456ull);

  detect_mask_mode<<<1,256,0,stream>>>((const u8*)done_raw, 32768, flag);
  convert_masks<<<64,256,0,stream>>>(done_raw, main_raw, dmask, mmask, 32768, flag);
  cvt_f32_bf16<<<32768,256,0,stream>>>(x, xb, 8388608);
  transpose_to_bf16<<<dim3(64,16),256,0,stream>>>(Wi, WiT, 1024, 4096);
  transpose_to_bf16<<<dim3(64,16),256,0,stream>>>(Wh, WhT, 1024, 4096);
  init_hsel<<<1024,256,0,stream>>>(h1i, h2i, mmask, hs0);
  zero_flags<<<1,256,0,stream>>>(ready, 256);

  if(zf32) gemm_zx<true ><<<8192,256,0,stream>>>(xb, WiT, bias, Zx, 32768, 4096, 1024);
  else     gemm_zx<false><<<8192,256,0,stream>>>(xb, WiT, bias, Zx, 32768, 4096, 1024);

  if(zf32)
    lstm_persist<true ><<<256,512,0,stream>>>(Zx,WhT,hs0,hs1,c1i,h1i,c2i,h2i,dmask,mmask,out,ready);
  else
    lstm_persist<false><<<256,512,0,stream>>>(Zx,WhT,hs0,hs1,c1i,h1i,c2i,h2i,dmask,mmask,out,ready);
}

// Round 6
// 1102.854 us; speedup vs baseline: 5.7170x; 1.0226x over previous
//
#include <hip/hip_runtime.h>
#include <cstdint>
#include <cstddef>

typedef unsigned short u16;
typedef unsigned char u8;
typedef unsigned int u32;

typedef short s16x8 __attribute__((ext_vector_type(8)));
typedef float f32x4 __attribute__((ext_vector_type(4)));

// ---------------- helpers ----------------
__device__ __forceinline__ float b2f(u16 h){ u32 u = ((u32)h)<<16; float f; __builtin_memcpy(&f,&u,4); return f; }
__device__ __forceinline__ u16 f2b(float x){ u32 u; __builtin_memcpy(&u,&x,4); u += 0x7fffu + ((u>>16)&1u); return (u16)(u>>16); }
__device__ __forceinline__ float sigf(float x){ return 1.f/(1.f+__expf(-x)); }
__device__ __forceinline__ float tanh2(float x){
  float ax=fabsf(x); float e=__expf(-2.f*ax); float r=(1.f-e)/(1.f+e); return x<0.f? -r : r;
}

typedef __attribute__((address_space(1))) const void gvoid_t;
typedef __attribute__((address_space(3))) void lvoid_t;
__device__ __forceinline__ void gl_lds16(const u16* src, u16* dst){
  __builtin_amdgcn_global_load_lds((gvoid_t*)src, (lvoid_t*)dst, 16, 0, 0);
}

// coherent write-through store (to coherence point; no L2 dirtying)
__device__ __forceinline__ void st_u16_coh(u16* p, u16 v){
  asm volatile("global_store_short %0, %1, off sc0 sc1" :: "v"(p), "v"((u32)v) : "memory");
}
__device__ __forceinline__ void st_f32_coh(float* p, float v){
  asm volatile("global_store_dword %0, %1, off sc0 sc1" :: "v"(p), "v"(v) : "memory");
}
// pinned (non-rematerializable) 16B loads
__device__ __forceinline__ s16x8 gload16(const u16* p){
  s16x8 r;
  asm volatile("global_load_dwordx4 %0, %1, off" : "=v"(r) : "v"(p) : "memory");
  return r;
}
// coherent 16B load: reads at coherence point (never stale; no invalidate needed)
__device__ __forceinline__ s16x8 gload16_coh(const u16* p){
  s16x8 r;
  asm volatile("global_load_dwordx4 %0, %1, off sc0 sc1" : "=v"(r) : "v"(p) : "memory");
  return r;
}

// ---------------- mask dtype detection + canonicalization ----------------
__global__ void detect_mask_mode(const u8* raw, int n, int* flag){
  __shared__ int cnt;
  int tid = threadIdx.x;
  if(tid==0) cnt=0;
  __syncthreads();
  int c=0;
  for(int i=tid;i<n;i+=blockDim.x) c += (raw[i]!=0);
  atomicAdd(&cnt, c);
  __syncthreads();
  if(tid==0) *flag = (cnt > (n>>2)) ? 1 : 0;  // 1 => byte-per-element layout
}

__global__ void convert_masks(const void* done_raw, const void* main_raw, u8* done_u8, u8* main_u8, int n, const int* flag){
  int mode = *flag;
  for(int i = blockIdx.x*blockDim.x + threadIdx.x; i<n; i += gridDim.x*blockDim.x){
    u8 d, m;
    if(mode){ d = ((const u8*)done_raw)[i]!=0; m = ((const u8*)main_raw)[i]!=0; }
    else    { d = ((const int*)done_raw)[i]!=0; m = ((const int*)main_raw)[i]!=0; }
    done_u8[i]=d; main_u8[i]=m;
  }
}

__global__ void zero_flags(int* p, int n){
  int i = threadIdx.x;
  if(i<n) p[i]=0;
}

// ---------------- conversions ----------------
__global__ void cvt_f32_bf16(const float* __restrict__ in, u16* __restrict__ out, int n4){
  int i = blockIdx.x*blockDim.x + threadIdx.x;
  if(i < n4){
    float4 v = ((const float4*)in)[i];
    ushort4 o;
    o.x=f2b(v.x); o.y=f2b(v.y); o.z=f2b(v.z); o.w=f2b(v.w);
    ((ushort4*)out)[i]=o;
  }
}

// in [R][C] f32  ->  out [C][R] bf16
__global__ void transpose_to_bf16(const float* __restrict__ in, u16* __restrict__ out, int R, int C){
  __shared__ float tile[64][65];
  int c0 = blockIdx.x*64, r0 = blockIdx.y*64;
  int tx = threadIdx.x & 63, ty = threadIdx.x >> 6;   // 256 threads
  for(int i=ty;i<64;i+=4) tile[i][tx] = in[(size_t)(r0+i)*C + c0 + tx];
  __syncthreads();
  for(int i=ty;i<64;i+=4) out[(size_t)(c0+i)*R + r0 + tx] = f2b(tile[tx][i]);
}

__global__ void init_hsel(const float* __restrict__ h1in, const float* __restrict__ h2in,
                          const u8* __restrict__ mmain, u16* __restrict__ hsel0){
  int i = blockIdx.x*blockDim.x + threadIdx.x;
  if(i < 256*1024){
    int row = i >> 10;
    hsel0[i] = f2b(mmain[row] ? h1in[i] : h2in[i]);
  }
}

// ---------------- phase 1: Zx = x @ Wi + b  (m97-style 128x128 tile) ----------------
template<bool ZF32>
__global__ __launch_bounds__(256) void gemm_zx(const u16* __restrict__ A, const u16* __restrict__ Bt,
                                               const float* __restrict__ bias, void* __restrict__ Cout,
                                               int M, int N, int K){
  __shared__ u16 As[128*32];
  __shared__ u16 Bs[128*32];
  int nbx = N>>7, nby = M>>7;
  int nwg = nbx*nby;                 // 8192, divisible by 8
  int gid = blockIdx.x;
  int per = nwg>>3;
  int g2 = (gid&7)*per + (gid>>3);   // XCD-contiguous remap (bijective: nwg%8==0)
  int tpg = 8*nbx;                   // 8-row supergroup x all cols
  int grp = g2/tpg, w = g2%tpg;
  int brow = grp*8 + (w & 7);
  int bcol = w >> 3;
  int row0 = brow<<7, col0 = bcol<<7;

  int tid=threadIdx.x, wid=tid>>6, lane=tid&63;
  int l15=lane&15, hi=lane>>4;
  int wm=(wid>>1)<<6, wn=(wid&1)<<6;

  f32x4 acc[4][4];
  #pragma unroll
  for(int m=0;m<4;m++)
    #pragma unroll
    for(int n=0;n<4;n++) acc[m][n]=(f32x4){0.f,0.f,0.f,0.f};

  for(int k0=0;k0<K;k0+=32){
    __syncthreads();
    #pragma unroll
    for(int q=0;q<2;q++){
      int cb=q*256+wid*64;
      int ch=cb+lane;
      gl_lds16(A + (size_t)(row0+(ch>>2))*K + k0 + (ch&3)*8, &As[cb*8]);
    }
    #pragma unroll
    for(int q=0;q<2;q++){
      int cb=q*256+wid*64;
      int ch=cb+lane;
      gl_lds16(Bt + (size_t)(col0+(ch>>2))*K + k0 + (ch&3)*8, &Bs[cb*8]);
    }
    __syncthreads();
    s16x8 a[4], b[4];
    #pragma unroll
    for(int m=0;m<4;m++) a[m] = *(const s16x8*)&As[(wm+m*16+l15)*32 + hi*8];
    #pragma unroll
    for(int n=0;n<4;n++) b[n] = *(const s16x8*)&Bs[(wn+n*16+l15)*32 + hi*8];
    #pragma unroll
    for(int m=0;m<4;m++)
      #pragma unroll
      for(int n=0;n<4;n++)
        acc[m][n] = __builtin_amdgcn_mfma_f32_16x16x32_bf16(a[m],b[n],acc[m][n],0,0,0);
  }
  #pragma unroll
  for(int m=0;m<4;m++){
    #pragma unroll
    for(int n=0;n<4;n++){
      #pragma unroll
      for(int j=0;j<4;j++){
        int r = row0+wm+m*16+hi*4+j;
        int c = col0+wn+n*16+l15;
        float v = acc[m][n][j] + bias[c];
        if(ZF32) ((float*)Cout)[(size_t)r*N+c]=v;
        else     ((u16*)Cout)[(size_t)r*N+c]=f2b(v);
      }
    }
  }
}

// ---------------- phase 2: persistent recurrent kernel (K-split waves) ----------------
// 256 blocks x 512 threads (8 waves), 1 block/CU. rg=bid&7 (32 rows), jg=bid>>3
// (32 hcols). Wave wid: gate=wid>>1, kg=wid&1 (K-half). Each wave: 32 rows x
// 32 gate-cols x K=512 -> reads only HALF the A-tile from LDS (256 KB/step/CU
// vs 512 in R5 -- the R5 bottleneck). B (Wh^T frags) = 128 VGPR/wave via pinned
// asm loads; waves_per_eu(2,2) gives the 256-reg budget. K-half partial sums
// exchanged via padded zpart LDS buffer. Sync unchanged from R5 (proven):
// sc0sc1 write-through h + vmcnt(0) + relaxed flag; sc0sc1 point-reads; no
// cache maintenance anywhere.
template<bool ZF32>
__global__ __launch_bounds__(512) __attribute__((amdgpu_waves_per_eu(2,2)))
void lstm_persist(
    const void* __restrict__ Zx, const u16* __restrict__ Wht,
    u16* __restrict__ hs0, u16* __restrict__ hs1,
    const float* __restrict__ c1i, const float* __restrict__ h1i,
    const float* __restrict__ c2i, const float* __restrict__ h2i,
    const u8* __restrict__ mdone, const u8* __restrict__ mmain,
    float* __restrict__ out, int* __restrict__ ready)
{
  __shared__ u16 As[32768];            // 64 KB: 128 chunks x [32 rows x 16B], XOR-swizzled
  __shared__ float zpart[4*2*32*33];   // 33 KB: [gate][kg][row][33] partial sums

  const int bid = blockIdx.x;
  const int rg = bid & 7, jg = bid >> 3;
  const int r0 = rg << 5, j0 = jg << 5;
  const int tid = threadIdx.x, wid = tid >> 6, lane = tid & 63;
  const int l15 = lane & 15, hi = lane >> 4;
  const int gate = wid >> 1, kg = wid & 1;
  const int srow = tid >> 4, sc16 = tid & 15;   // staging: row 0..31, col16 0..15
  const int erow = tid >> 5, ecol = tid & 31;   // epilogue: rows, 32 cols

  // ---- Wh^T fragments: this wave's (gate, K-half) x 32 cols: 32 x s16x8 = 128 VGPRs ----
  s16x8 breg[2][16];
  {
    #pragma unroll
    for(int n=0;n<2;n++){
      const u16* wp = Wht + ((size_t)(gate*1024 + j0 + n*16 + l15))*1024 + kg*512 + hi*8;
      #pragma unroll
      for(int kk=0;kk<16;kk++) breg[n][kk] = gload16(wp + kk*32);
    }
    asm volatile("s_waitcnt vmcnt(0)" ::: "memory");
    __builtin_amdgcn_sched_barrier(0);
  }

  // ---- states into registers (thread-stationary across all 128 steps) ----
  float c1r[2],c2r[2],h1r[2],h2r[2];
  #pragma unroll
  for(int e=0;e<2;e++){
    size_t sidx = (size_t)(r0 + e*16 + erow)*1024 + j0 + ecol;
    c1r[e]=c1i[sidx]; c2r[e]=c2i[sidx]; h1r[e]=h1i[sidx]; h2r[e]=h2i[sidx];
  }

  const u16* Zb = (const u16*)Zx;
  const float* Zf = (const float*)Zx;
  int* flag = ready + rg*32;    // 128B-spaced per-rg counters

  for(int t=0;t<128;t++){
    // ---- prefetch step-local immutable inputs (cached; overlap the spin) ----
    float zr[4][2]; u8 md[2], mm[2], mm2[2];
    #pragma unroll
    for(int e=0;e<2;e++){
      int gb = t*256 + r0 + e*16 + erow;
      size_t base = (size_t)gb*4096 + j0 + ecol;
      #pragma unroll
      for(int g=0; g<4; g++)
        zr[g][e] = ZF32 ? Zf[base + g*1024] : b2f(Zb[base + g*1024]);
      md[e]=mdone[gb]; mm[e]=mmain[gb];
      mm2[e] = (t<127) ? mmain[gb+256] : (u8)0;
    }

    // ---- chain wait (single spinner; others park at the barrier) ----
    if(t>0 && tid==0){
      while(__hip_atomic_load(flag, __ATOMIC_RELAXED, __HIP_MEMORY_SCOPE_AGENT) < 32*t)
        __builtin_amdgcn_s_sleep(1);
    }
    __syncthreads();
    __builtin_amdgcn_sched_barrier(0);

    const u16* hin = (t&1) ? hs1 : hs0;
    u16* hout = (t&1) ? hs0 : hs1;

    // ---- stage h tile: 8 coherent 16B loads/thread -> swizzled LDS,
    //      ds_writes interleaved with counted vmcnt ----
    {
      const u16* hrow = hin + (size_t)(r0+srow)*1024;
      s16x8 v[8];
      #pragma unroll
      for(int kc=0;kc<8;kc++) v[kc] = gload16_coh(hrow + (kc*16+sc16)*8);
      asm volatile("s_waitcnt vmcnt(4)" ::: "memory");
      #pragma unroll
      for(int kc=0;kc<4;kc++){
        int chunk = kc*16+sc16;
        *(s16x8*)&As[chunk*256 + ((srow ^ (chunk&7))<<3)] = v[kc];
      }
      asm volatile("s_waitcnt vmcnt(0)" ::: "memory");
      #pragma unroll
      for(int kc=4;kc<8;kc++){
        int chunk = kc*16+sc16;
        *(s16x8*)&As[chunk*256 + ((srow ^ (chunk&7))<<3)] = v[kc];
      }
    }
    __syncthreads();   // tile staged

    // ---- recurrent GEMM: this wave's K-half, 64 MFMA, B from registers ----
    f32x4 acc[2][2];
    #pragma unroll
    for(int m=0;m<2;m++)
      #pragma unroll
      for(int n=0;n<2;n++) acc[m][n]=(f32x4){0.f,0.f,0.f,0.f};
    #pragma unroll
    for(int kk=0;kk<16;kk++){
      int c0 = (kg*16 + kk)*4 + hi;                 // 16B chunk 0..127
      s16x8 a0 = *(const s16x8*)&As[c0*256 + ((l15      ^ (c0&7))<<3)];
      s16x8 a1 = *(const s16x8*)&As[c0*256 + (((16+l15) ^ (c0&7))<<3)];
      acc[0][0] = __builtin_amdgcn_mfma_f32_16x16x32_bf16(a0, breg[0][kk], acc[0][0], 0,0,0);
      acc[0][1] = __builtin_amdgcn_mfma_f32_16x16x32_bf16(a0, breg[1][kk], acc[0][1], 0,0,0);
      acc[1][0] = __builtin_amdgcn_mfma_f32_16x16x32_bf16(a1, breg[0][kk], acc[1][0], 0,0,0);
      acc[1][1] = __builtin_amdgcn_mfma_f32_16x16x32_bf16(a1, breg[1][kk], acc[1][1], 0,0,0);
    }
    // no barrier needed: zpart is a separate LDS region

    // ---- K-half partial exchange: zpart[gate][kg][row][33] ----
    #pragma unroll
    for(int m=0;m<2;m++)
      #pragma unroll
      for(int n=0;n<2;n++)
        #pragma unroll
        for(int j=0;j<4;j++){
          int row = m*16 + hi*4 + j;
          zpart[((gate*2+kg)*32 + row)*33 + n*16 + l15] = acc[m][n][j];
        }
    __syncthreads();

    // ---- epilogue: sum K-halves, gates, state update; h stores first ----
    float nhv[2];
    #pragma unroll
    for(int e=0;e<2;e++){
      int row = e*16 + erow;
      float zi  = zr[0][e] + zpart[((0)*32+row)*33 + ecol] + zpart[((1)*32+row)*33 + ecol];
      float zf_ = zr[1][e] + zpart[((2)*32+row)*33 + ecol] + zpart[((3)*32+row)*33 + ecol];
      float zg  = zr[2][e] + zpart[((4)*32+row)*33 + ecol] + zpart[((5)*32+row)*33 + ecol];
      float zo  = zr[3][e] + zpart[((6)*32+row)*33 + ecol] + zpart[((7)*32+row)*33 + ecol];
      bool m_ = mm[e]!=0, d_ = md[e]!=0;
      float co = m_ ? c1r[e] : c2r[e];
      float nc = sigf(zf_)*co + sigf(zi)*tanh2(zg);
      float nhx = sigf(zo)*tanh2(nc);
      nhv[e] = nhx;
      float n1c = m_?nc:c1r[e], n2c = m_?c2r[e]:nc;
      float n1h = m_?nhx:h1r[e], n2h = m_?h2r[e]:nhx;
      if(d_){ n1c=0.f; n2c=0.f; n1h=0.f; n2h=0.f; }
      c1r[e]=n1c; c2r[e]=n2c; h1r[e]=n1h; h2r[e]=n2h;
      if(t<127)
        st_u16_coh(&hout[(size_t)(r0+row)*1024 + j0 + ecol], f2b(mm2[e] ? n1h : n2h));
    }
    asm volatile("s_waitcnt vmcnt(0)" ::: "memory");   // h at coherence point
    __syncthreads();
    if(t<127 && tid==0)
      __hip_atomic_fetch_add(flag, 1, __ATOMIC_RELAXED, __HIP_MEMORY_SCOPE_AGENT);

    // ---- out store off the critical path (drains during next spin) ----
    #pragma unroll
    for(int e=0;e<2;e++){
      int gb = t*256 + r0 + e*16 + erow;
      st_f32_coh(&out[(size_t)gb*1024 + j0 + ecol], nhv[e]);
    }
  }
}

// ---------------- host ----------------
extern "C" void kernel_launch(void* const* d_in, const int* in_sizes, int n_in,
                              void* d_out, int out_size, void* d_ws, size_t ws_size,
                              hipStream_t stream){
  const float* x   = (const float*)d_in[0];
  const float* c1i = (const float*)d_in[1];
  const float* h1i = (const float*)d_in[2];
  const float* c2i = (const float*)d_in[3];
  const float* h2i = (const float*)d_in[4];
  const float* Wi  = (const float*)d_in[5];
  const float* Wh  = (const float*)d_in[6];
  const float* bias= (const float*)d_in[7];
  const void* done_raw = d_in[8];
  const void* main_raw = d_in[9];
  float* out = (float*)d_out;

  char* ws = (char*)d_ws;
  size_t off=0;
  auto alloc=[&](size_t sz)->char*{ char* p = ws+off; off += (sz+255)&~(size_t)255; return p; };

  u16* xb   = (u16*)alloc(33554432ull*2);        // x as bf16 [32768][1024]
  u16* WiT  = (u16*)alloc(4096ull*1024*2);       // Wi^T bf16 [4096][1024]
  u16* WhT  = (u16*)alloc(4096ull*1024*2);       // Wh^T bf16 [4096][1024]
  u16* hs0  = (u16*)alloc(262144ull*2);
  u16* hs1  = (u16*)alloc(262144ull*2);
  u8* dmask = (u8*)alloc(32768);
  u8* mmask = (u8*)alloc(32768);
  int* flag = (int*)alloc(256);
  int* ready= (int*)alloc(1024);

  bool zf32 = (off + 536870912ull) <= ws_size;   // Zx fp32 if workspace allows
  void* Zx  = (void*)alloc(zf32 ? 536870912ull : 268435456ull);

  detect_mask_mode<<<1,256,0,stream>>>((const u8*)done_raw, 32768, flag);
  convert_masks<<<64,256,0,stream>>>(done_raw, main_raw, dmask, mmask, 32768, flag);
  cvt_f32_bf16<<<32768,256,0,stream>>>(x, xb, 8388608);
  transpose_to_bf16<<<dim3(64,16),256,0,stream>>>(Wi, WiT, 1024, 4096);
  transpose_to_bf16<<<dim3(64,16),256,0,stream>>>(Wh, WhT, 1024, 4096);
  init_hsel<<<1024,256,0,stream>>>(h1i, h2i, mmask, hs0);
  zero_flags<<<1,256,0,stream>>>(ready, 256);

  if(zf32) gemm_zx<true ><<<8192,256,0,stream>>>(xb, WiT, bias, Zx, 32768, 4096, 1024);
  else     gemm_zx<false><<<8192,256,0,stream>>>(xb, WiT, bias, Zx, 32768, 4096, 1024);

  if(zf32)
    lstm_persist<true ><<<256,512,0,stream>>>(Zx,WhT,hs0,hs1,c1i,h1i,c2i,h2i,dmask,mmask,out,ready);
  else
    lstm_persist<false><<<256,512,0,stream>>>(Zx,WhT,hs0,hs1,c1i,h1i,c2i,h2i,dmask,mmask,out,ready);
}